// Round 1
// baseline (464.352 us; speedup 1.0000x reference)
//
#include <hip/hip_runtime.h>

// Problem constants (GCN_61065845014917)
#define B_   4
#define C_   1024
#define D_   768
#define H_   12
#define E_   32
#define K_   2
#define S_   24
#define V_   8
#define P_   512
#define NT_  256
#define EMB_ 768
#define BLK_ 64
#define NL_  97
#define DNT_ 1024     // D+NT
#define KHT_ 1792     // 2D+NT
#define KBIL_ 49152   // EMB*BLK
#define NPAD_ 128     // NL padded for MFMA

typedef __bf16 bf16x8 __attribute__((ext_vector_type(8)));
typedef float  f32x4  __attribute__((ext_vector_type(4)));

__device__ __forceinline__ float b2f(unsigned short u) {
    return (float)__builtin_bit_cast(__bf16, u);
}
__device__ __forceinline__ unsigned short f2b(float f) {
    return __builtin_bit_cast(unsigned short, (__bf16)f);   // RNE
}
// dtype-dispatched input load / output store (isf=1: f32 buffers, isf=0: bf16)
__device__ __forceinline__ float ld_in(const void* p, size_t i, int isf) {
    return isf ? ((const float*)p)[i] : b2f(((const unsigned short*)p)[i]);
}
__device__ __forceinline__ void st_out(void* p, size_t i, float v, int isf) {
    if (isf) ((float*)p)[i] = v;
    else     ((unsigned short*)p)[i] = f2b(v);
}
// per-wave inline dtype probe: 64 even-index ushorts of sequence_output.
__device__ __forceinline__ int probe_isf(const void* seq) {
    unsigned short u = ((const unsigned short*)seq)[2 * (threadIdx.x & 63)];
    int huge = !(fabsf(b2f(u)) <= 1e10f);          // catches NaN
    unsigned long long zb = __ballot(u == 0);
    return __any(huge) || (__popcll(zb) > 56);
}

// ---------------------------------------------------------------------------
// K1 fused prep: [0,256) gather, [256,1792) eatt, [1792,2560) t_seq,
//                [2560,3232) t_w, [3232,4000) t_bil(64k/blk)
#define PREP_GATHER 256
#define PREP_EATT   (PREP_GATHER + B_*E_*H_)     // +1536 -> 1792
#define PREP_TSEQ   (PREP_EATT + 768)            // -> 2560
#define PREP_TW     (PREP_TSEQ + 672)            // -> 3232
#define PREP_TBIL   (PREP_TW + 768)              // -> 4000

__global__ __launch_bounds__(256) void k_prep(
    const void* __restrict__ seq, const void* __restrict__ att,
    const int* __restrict__ epos, const int* __restrict__ spos,
    const int* __restrict__ vpos, const void* __restrict__ ntype,
    const void* __restrict__ Wh, const void* __restrict__ Wt_,
    const void* __restrict__ Wb,
    float* __restrict__ enth, unsigned short* __restrict__ e_att,
    unsigned short* __restrict__ seqT,
    unsigned short* __restrict__ WtH, unsigned short* __restrict__ WtT,
    unsigned short* __restrict__ WtB,
    void* __restrict__ outv, long long moff, long long soff, long long voff)
{
    __shared__ __align__(16) unsigned char smem[12544];
    int blk = blockIdx.x, tid = threadIdx.x;
    int isf = probe_isf(seq);
    if (blk < PREP_GATHER) {
        if (blk < B_ * E_) {
            int b = blk / E_, e = blk % E_;
            int i0 = epos[(b * E_ + e) * K_ + 0] + 1;
            int i1 = epos[(b * E_ + e) * K_ + 1] + 1;
            size_t r0 = ((size_t)b * C_ + i0) * D_;
            size_t r1 = ((size_t)b * C_ + i1) * D_;
            size_t m0 = (size_t)moff + ((size_t)(b * E_ * K_) + 2 * e) * D_;
            size_t m1 = m0 + D_;
            float* eh = enth + (size_t)(b * E_ + e) * DNT_;
            for (int d = tid; d < D_; d += 256) {
                float a = ld_in(seq, r0 + d, isf);
                float c = ld_in(seq, r1 + d, isf);
                st_out(outv, m0 + d, a, isf);
                st_out(outv, m1 + d, c, isf);
                float mx = fmaxf(a, c);
                eh[d] = mx + logf(expf(a - mx) + expf(c - mx));
            }
            size_t nt0 = (size_t)(b * E_ + e) * NT_;
            for (int j = tid; j < NT_; j += 256) eh[D_ + j] = ld_in(ntype, nt0 + j, isf);
        } else if (blk < B_ * E_ + B_ * S_) {
            int t = blk - B_ * E_; int b = t / S_, s = t % S_;
            int i = spos[b * S_ + s] + 1;
            size_t r = ((size_t)b * C_ + i) * D_;
            size_t o = (size_t)soff + (size_t)(b * S_ + s) * D_;
            for (int d = tid; d < D_; d += 256) st_out(outv, o + d, ld_in(seq, r + d, isf), isf);
        } else {
            int t = blk - B_ * E_ - B_ * S_; int b = t / V_, v = t % V_;
            int i = vpos[b * V_ + v] + 1;
            size_t r = ((size_t)b * C_ + i) * D_;
            size_t o = (size_t)voff + (size_t)(b * V_ + v) * D_;
            for (int d = tid; d < D_; d += 256) st_out(outv, o + d, ld_in(seq, r + d, isf), isf);
        }
    } else if (blk < PREP_EATT) {
        int t = blk - PREP_GATHER;
        int b = t / (E_ * H_); int r = t % (E_ * H_); int e = r / H_; int h = r % H_;
        int i0 = epos[(b * E_ + e) * K_ + 0] + 1;
        int i1 = epos[(b * E_ + e) * K_ + 1] + 1;
        size_t a0 = (((size_t)b * H_ + h) * C_ + i0) * C_;
        size_t a1 = (((size_t)b * H_ + h) * C_ + i1) * C_;
        unsigned short* o = e_att + (((size_t)(b * E_ + e)) * H_ + h) * C_;
        for (int c = tid; c < C_; c += 256)
            o[c] = f2b(0.5f * (ld_in(att, a0 + c, isf) + ld_in(att, a1 + c, isf)));
    } else if (blk < PREP_TSEQ) {
        int t = blk - PREP_EATT;                 // b*192 + ct*12 + dt
        int b = t / 192; int r = t % 192; int ct = r / 12; int dt = r % 12;
        typedef unsigned short row65[65];
        row65* tile = (row65*)smem;
        for (int idx = tid; idx < 4096; idx += 256) {
            int cc = idx >> 6, dd = idx & 63;
            tile[cc][dd] = f2b(ld_in(seq, ((size_t)b * C_ + ct * 64 + cc) * D_ + dt * 64 + dd, isf));
        }
        __syncthreads();
        for (int idx = tid; idx < 4096; idx += 256) {
            int dd = idx >> 6, cc = idx & 63;
            seqT[((size_t)b * D_ + dt * 64 + dd) * C_ + ct * 64 + cc] = tile[cc][dd];
        }
    } else if (blk < PREP_TW) {
        int t = blk - PREP_TSEQ;                 // mat*336 + kt*12 + nt
        int mat = t / 336; int r = t % 336; int kt = r / 12; int nt = r % 12;
        const void* in = mat ? Wt_ : Wh;
        unsigned short* out = mat ? WtT : WtH;
        typedef unsigned short row65[65];
        row65* tile = (row65*)smem;
        for (int idx = tid; idx < 4096; idx += 256) {
            int kk = idx >> 6, nn = idx & 63;
            tile[kk][nn] = f2b(ld_in(in, ((size_t)kt * 64 + kk) * EMB_ + nt * 64 + nn, isf));
        }
        __syncthreads();
        for (int idx = tid; idx < 4096; idx += 256) {
            int nn = idx >> 6, kk = idx & 63;
            out[((size_t)nt * 64 + nn) * KHT_ + kt * 64 + kk] = tile[kk][nn];
        }
    } else {
        int t = blk - PREP_TW;                   // 64 k-cols per block
        int k0 = t << 6;
        unsigned short* raw = (unsigned short*)smem;   // [64*97]
        for (int idx = tid; idx < 64 * NL_; idx += 256)
            raw[idx] = f2b(ld_in(Wb, (size_t)k0 * NL_ + idx, isf));
        __syncthreads();
        int kk = tid & 63, nq = tid >> 6;              // 4 quarters x 32 n
        for (int i = 0; i < 32; i++) {
            int n = nq * 32 + i;
            unsigned short v = (n < NL_) ? raw[kk * NL_ + n] : (unsigned short)0;
            WtB[(size_t)n * KBIL_ + k0 + kk] = v;
        }
    }
}

// ---------------------------------------------------------------------------
// K2 fused mid: [0,2048) htatt, [2048,4096) xbuild, [4096,4352) zero logitsF
__global__ __launch_bounds__(256) void k_mid(
    const unsigned short* __restrict__ e_att, const float* __restrict__ enth,
    const int* __restrict__ hts,
    unsigned short* __restrict__ htb,
    unsigned short* __restrict__ Xh, unsigned short* __restrict__ Xt,
    float* __restrict__ logitsF)
{
    __shared__ float red[4];
    int blk = blockIdx.x, tid = threadIdx.x;
    if (blk < B_ * P_) {
        int b = blk >> 9;
        int he = hts[blk * 2 + 0], te = hts[blk * 2 + 1];
        const unsigned short* ph = e_att + (size_t)(b * E_ + he) * H_ * C_;
        const unsigned short* pt = e_att + (size_t)(b * E_ + te) * H_ * C_;
        float v[4]; float ls = 0.f;
        for (int ci = 0; ci < 4; ci++) {
            int c = tid + (ci << 8);
            float acc = 0.f;
#pragma unroll
            for (int h = 0; h < H_; h++) acc += b2f(ph[h * C_ + c]) * b2f(pt[h * C_ + c]);
            acc *= (1.0f / (float)H_);
            v[ci] = acc; ls += acc;
        }
        for (int off = 32; off > 0; off >>= 1) ls += __shfl_down(ls, off, 64);
        if ((tid & 63) == 0) red[tid >> 6] = ls;
        __syncthreads();
        float inv = 1.0f / (red[0] + red[1] + red[2] + red[3] + 1e-5f);
        for (int ci = 0; ci < 4; ci++)
            htb[((size_t)blk << 10) + tid + (ci << 8)] = f2b(v[ci] * inv);
    } else if (blk < 2 * B_ * P_) {
        int m = blk - B_ * P_; int b = m >> 9;
        int eh = hts[m * 2 + 0], et = hts[m * 2 + 1];
        const float* sh = enth + (size_t)(b * E_ + eh) * DNT_;
        const float* st = enth + (size_t)(b * E_ + et) * DNT_;
        for (int k = tid; k < DNT_; k += 256) {
            Xh[(size_t)m * KHT_ + k] = f2b(sh[k]);
            Xt[(size_t)m * KHT_ + k] = f2b(st[k]);
        }
    } else {
        int t = blk - 2 * B_ * P_;               // 256 blocks zero 1 MB
        ((float4*)logitsF)[(size_t)t * 256 + tid] = make_float4(0.f, 0.f, 0.f, 0.f);
    }
}

// ---------------------------------------------------------------------------
// bf16 MFMA GEMM, 64x64 tile, 4 waves 2x2, K-step 32, LDS staging (coalesced),
// register prefetch. (R5's LDS-free variant thrashed L2 -- reverted.)
// zmode 0 (rs): z = batch; epilogue writes bf16 into Xh/Xt cols DNT_+n.
// zmode 1 (ht): z = mat (0=head,1=tail); epilogue bf16 tanh(acc+bias) -> oY.
__global__ __launch_bounds__(256) void k_gemm(
    const unsigned short* __restrict__ A0, const unsigned short* __restrict__ A1,
    const unsigned short* __restrict__ B0, const unsigned short* __restrict__ B1,
    long long lda, long long ldb, long long sAz, long long sBz,
    int nsteps, int zmode,
    const void* __restrict__ bias0, const void* __restrict__ bias1,
    unsigned short* __restrict__ oY0, unsigned short* __restrict__ oY1,
    unsigned short* __restrict__ oX1, unsigned short* __restrict__ oX2,
    const void* __restrict__ seq)
{
    int n0 = blockIdx.x * 64, m0 = blockIdx.y * 64, z = blockIdx.z;
    const unsigned short* Ab; const unsigned short* Bb;
    unsigned short* oY = nullptr; const void* bias = nullptr;
    if (zmode == 0) {
        Ab = A0 + (size_t)z * sAz; Bb = B0 + (size_t)z * sBz;
    } else {
        Ab = z ? A1 : A0; Bb = z ? B1 : B0;
        oY = z ? oY1 : oY0; bias = z ? bias1 : bias0;
    }
    __shared__ __align__(16) unsigned short a_lds[64][40];
    __shared__ __align__(16) unsigned short b_lds[64][40];
    int tid = threadIdx.x, lane = tid & 63, w = tid >> 6;
    int wm = (w >> 1) * 32, wn = (w & 1) * 32, q = lane >> 4, l15 = lane & 15;
    f32x4 acc00 = {0.f,0.f,0.f,0.f}, acc01 = acc00, acc10 = acc00, acc11 = acc00;
    int srow = tid >> 2, sch = (tid & 3) * 8;
    const unsigned short* pa = Ab + (size_t)(m0 + srow) * lda + sch;
    const unsigned short* pb = Bb + (size_t)(n0 + srow) * ldb + sch;
    int4 ra = *(const int4*)pa;
    int4 rb = *(const int4*)pb;
    for (int ks = 0; ks < nsteps; ks++) {
        __syncthreads();
        *(int4*)&a_lds[srow][sch] = ra;
        *(int4*)&b_lds[srow][sch] = rb;
        __syncthreads();
        if (ks + 1 < nsteps) {
            ra = *(const int4*)(pa + (size_t)(ks + 1) * 32);
            rb = *(const int4*)(pb + (size_t)(ks + 1) * 32);
        }
        bf16x8 a0 = *(const bf16x8*)&a_lds[wm + l15][q * 8];
        bf16x8 a1 = *(const bf16x8*)&a_lds[wm + 16 + l15][q * 8];
        bf16x8 b0 = *(const bf16x8*)&b_lds[wn + l15][q * 8];
        bf16x8 b1 = *(const bf16x8*)&b_lds[wn + 16 + l15][q * 8];
        acc00 = __builtin_amdgcn_mfma_f32_16x16x32_bf16(a0, b0, acc00, 0, 0, 0);
        acc01 = __builtin_amdgcn_mfma_f32_16x16x32_bf16(a0, b1, acc01, 0, 0, 0);
        acc10 = __builtin_amdgcn_mfma_f32_16x16x32_bf16(a1, b0, acc10, 0, 0, 0);
        acc11 = __builtin_amdgcn_mfma_f32_16x16x32_bf16(a1, b1, acc11, 0, 0, 0);
    }
    f32x4 accs[2][2] = {{acc00, acc01}, {acc10, acc11}};
    int isf = (zmode == 1) ? probe_isf(seq) : 0;
#pragma unroll
    for (int mt = 0; mt < 2; mt++)
#pragma unroll
        for (int nt = 0; nt < 2; nt++) {
            int gmb = m0 + wm + mt * 16 + q * 4;
            int gn  = n0 + wn + nt * 16 + l15;
            if (zmode == 0) {
#pragma unroll
                for (int r = 0; r < 4; r++) {
                    unsigned short v = f2b(accs[mt][nt][r]);
                    size_t o = (size_t)(z * P_ + gmb + r) * KHT_ + DNT_ + gn;
                    oX1[o] = v; oX2[o] = v;
                }
            } else {
                float bv = ld_in(bias, gn, isf);
#pragma unroll
                for (int r = 0; r < 4; r++)
                    oY[(size_t)(gmb + r) * EMB_ + gn] = f2b(tanhf(accs[mt][nt][r] + bv));
            }
        }
}

// ---------------------------------------------------------------------------
// Grouped bilinear via MFMA — restructured (R_new):
//   logits[m,n] = sum_i hs[m,i] * ( sum_j ts[m,j] * W[i,j,n] )
// Inner MFMA computes P_i = ts_frag x W_i with UNSCALED bf16 ts fragments
// (loop-invariant over i!); hs is folded in post-MFMA as 16 f32 FMAs per i.
// This removes the per-kk scalar hs*ts build (16 mul + 16 cvt per kk) that
// made the old loop ~4:1 VALU:MFMA issue-bound, and improves accuracy
// (product no longer rounded to bf16 pre-MFMA).
// M-tile 64 (8 waves, 2m x 4n) halves WtB re-reads to 384 MB, and the
// XCD-affinity remap gives each XCD a contiguous (g, mtile) chunk so its
// WtB working set (<=2 group slices = 2 MB) stays in its 4 MB L2 instead of
// thrashing Infinity Cache.
__global__ __launch_bounds__(512) void k_bil(
    const unsigned short* __restrict__ hsB, const unsigned short* __restrict__ tsB,
    const unsigned short* __restrict__ WtB, float* __restrict__ logitsF)
{
    // 384 blocks = 8 XCDs x 48; lin sweeps (g, mtile) contiguously per XCD.
    int bid = blockIdx.x;
    int lin = (bid & 7) * 48 + (bid >> 3);
    int g   = lin >> 5;            // [0,12)
    int m0  = (lin & 31) * 64;     // [0,2048) in 64-row tiles

    int tid = threadIdx.x, lane = tid & 63, w = tid >> 6;
    int q = lane >> 4, l15 = lane & 15;
    int wm = (w >> 2) * 32;        // 0 / 32  (m-half)
    int wn = (w & 3) * 16;         // 0,16,32,48 (n-tile; +64 for 2nd)

    __shared__ __align__(16) unsigned short tsl[64][72];  // stride 144B: 2-way banks, 16B-aligned
    __shared__ __align__(16) unsigned short hsT[64][64];  // [i][m] transposed for b64 broadcast
    {
        int m = tid >> 3, j0 = (tid & 7) * 8;
        const unsigned short* ph = &hsB[(size_t)(m0 + m) * EMB_ + g * 64 + j0];
        const unsigned short* pt = &tsB[(size_t)(m0 + m) * EMB_ + g * 64 + j0];
        ushort4 h0 = *(const ushort4*)ph, h1 = *(const ushort4*)(ph + 4);
        ushort4 t0 = *(const ushort4*)pt, t1 = *(const ushort4*)(pt + 4);
        *(ushort4*)&tsl[m][j0]     = t0;
        *(ushort4*)&tsl[m][j0 + 4] = t1;
        hsT[j0+0][m] = h0.x; hsT[j0+1][m] = h0.y; hsT[j0+2][m] = h0.z; hsT[j0+3][m] = h0.w;
        hsT[j0+4][m] = h1.x; hsT[j0+5][m] = h1.y; hsT[j0+6][m] = h1.z; hsT[j0+7][m] = h1.w;
    }
    __syncthreads();

    // ts A-fragments: invariant over i (j-range identical for every i)
    bf16x8 a00 = *(const bf16x8*)&tsl[wm + l15][q * 8];        // m-sub0, h=0
    bf16x8 a01 = *(const bf16x8*)&tsl[wm + l15][32 + q * 8];   // m-sub0, h=1
    bf16x8 a10 = *(const bf16x8*)&tsl[wm + 16 + l15][q * 8];   // m-sub1, h=0
    bf16x8 a11 = *(const bf16x8*)&tsl[wm + 16 + l15][32 + q * 8];

    const unsigned short* pW0 = WtB + (size_t)(wn + l15) * KBIL_ + g * 4096 + q * 8;
    const unsigned short* pW1 = pW0 + (size_t)64 * KBIL_;

    f32x4 acc00 = {0.f,0.f,0.f,0.f}, acc01 = acc00, acc10 = acc00, acc11 = acc00;
    const f32x4 zf = {0.f,0.f,0.f,0.f};

    bf16x8 wc0 = *(const bf16x8*)(pW0);
    bf16x8 wc1 = *(const bf16x8*)(pW0 + 32);
    bf16x8 wc2 = *(const bf16x8*)(pW1);
    bf16x8 wc3 = *(const bf16x8*)(pW1 + 32);
    bf16x8 wx0 = wc0, wx1 = wc1, wx2 = wc2, wx3 = wc3;

    for (int i = 0; i < 64; ++i) {
        if (i + 1 < 64) {
            const unsigned short* q0 = pW0 + (size_t)(i + 1) * 64;
            const unsigned short* q1 = pW1 + (size_t)(i + 1) * 64;
            wx0 = *(const bf16x8*)(q0); wx1 = *(const bf16x8*)(q0 + 32);
            wx2 = *(const bf16x8*)(q1); wx3 = *(const bf16x8*)(q1 + 32);
        }
        // P_i per (m-sub, n-tile): 2 chained MFMAs over the 64 j's
        f32x4 p00 = __builtin_amdgcn_mfma_f32_16x16x32_bf16(a00, wc0, zf, 0, 0, 0);
        p00       = __builtin_amdgcn_mfma_f32_16x16x32_bf16(a01, wc1, p00, 0, 0, 0);
        f32x4 p01 = __builtin_amdgcn_mfma_f32_16x16x32_bf16(a00, wc2, zf, 0, 0, 0);
        p01       = __builtin_amdgcn_mfma_f32_16x16x32_bf16(a01, wc3, p01, 0, 0, 0);
        f32x4 p10 = __builtin_amdgcn_mfma_f32_16x16x32_bf16(a10, wc0, zf, 0, 0, 0);
        p10       = __builtin_amdgcn_mfma_f32_16x16x32_bf16(a11, wc1, p10, 0, 0, 0);
        f32x4 p11 = __builtin_amdgcn_mfma_f32_16x16x32_bf16(a10, wc2, zf, 0, 0, 0);
        p11       = __builtin_amdgcn_mfma_f32_16x16x32_bf16(a11, wc3, p11, 0, 0, 0);

        // hs broadcast: rows wm + q*4..q*4+3 (and +16) of column i
        ushort4 hv0 = *(const ushort4*)&hsT[i][wm + q * 4];
        ushort4 hv1 = *(const ushort4*)&hsT[i][wm + 16 + q * 4];
        float ha00 = b2f(hv0.x), ha01 = b2f(hv0.y), ha02 = b2f(hv0.z), ha03 = b2f(hv0.w);
        float ha10 = b2f(hv1.x), ha11 = b2f(hv1.y), ha12 = b2f(hv1.z), ha13 = b2f(hv1.w);
        acc00[0] += ha00 * p00[0]; acc00[1] += ha01 * p00[1];
        acc00[2] += ha02 * p00[2]; acc00[3] += ha03 * p00[3];
        acc01[0] += ha00 * p01[0]; acc01[1] += ha01 * p01[1];
        acc01[2] += ha02 * p01[2]; acc01[3] += ha03 * p01[3];
        acc10[0] += ha10 * p10[0]; acc10[1] += ha11 * p10[1];
        acc10[2] += ha12 * p10[2]; acc10[3] += ha13 * p10[3];
        acc11[0] += ha10 * p11[0]; acc11[1] += ha11 * p11[1];
        acc11[2] += ha12 * p11[2]; acc11[3] += ha13 * p11[3];

        wc0 = wx0; wc1 = wx1; wc2 = wx2; wc3 = wx3;
    }
#pragma unroll
    for (int r = 0; r < 4; ++r) {
        atomicAdd(&logitsF[(size_t)(m0 + wm + q * 4 + r) * NPAD_ + wn + l15],           acc00[r]);
        atomicAdd(&logitsF[(size_t)(m0 + wm + q * 4 + r) * NPAD_ + wn + 64 + l15],      acc01[r]);
        atomicAdd(&logitsF[(size_t)(m0 + wm + 16 + q * 4 + r) * NPAD_ + wn + l15],      acc10[r]);
        atomicAdd(&logitsF[(size_t)(m0 + wm + 16 + q * 4 + r) * NPAD_ + wn + 64 + l15], acc11[r]);
    }
}

// ---------------------------------------------------------------------------
// final: logits out with bias, n<97
__global__ __launch_bounds__(256) void k_fin(
    const float* __restrict__ logitsF, const void* __restrict__ b_bil,
    void* __restrict__ outv, const void* __restrict__ seq)
{
    int isf = probe_isf(seq);
    int idx = blockIdx.x * 256 + threadIdx.x;
    if (idx >= B_ * P_ * NL_) return;
    int m = idx / NL_, n = idx % NL_;
    st_out(outv, idx, logitsF[(size_t)m * NPAD_ + n] + ld_in(b_bil, n, isf), isf);
}

// ---------------------------------------------------------------------------
extern "C" void kernel_launch(void* const* d_in, const int* in_sizes, int n_in,
                              void* d_out, int out_size, void* d_ws, size_t ws_size,
                              hipStream_t stream)
{
    const void* seq    = d_in[0];
    const void* att    = d_in[1];
    const int*  epos   = (const int*)d_in[2];
    const int*  spos   = (const int*)d_in[3];
    const int*  vpos   = (const int*)d_in[4];
    const int*  hts    = (const int*)d_in[5];
    const void* ntype  = d_in[6];
    const void* W_head = d_in[7];
    const void* b_head = d_in[8];
    const void* W_tail = d_in[9];
    const void* b_tail = d_in[10];
    const void* W_bil  = d_in[11];
    const void* b_bil  = d_in[12];

    // output element offsets (dtype-agnostic)
    long long mention_off = (long long)B_ * P_ * NL_;
    long long sent_off    = mention_off + (long long)B_ * E_ * K_ * D_;
    long long virt_off    = sent_off + (long long)B_ * S_ * D_;

    // workspace carve (~50 MB)
    char* p = (char*)d_ws;
    auto alloc = [&](size_t bytes) { void* r = (void*)p; p += (bytes + 255) & ~(size_t)255; return r; };
    unsigned short* e_att   = (unsigned short*)alloc((size_t)B_ * E_ * H_ * C_ * 2);
    unsigned short* htb     = (unsigned short*)alloc((size_t)B_ * P_ * C_ * 2);
    unsigned short* seqT    = (unsigned short*)alloc((size_t)B_ * D_ * C_ * 2);
    unsigned short* WtH     = (unsigned short*)alloc((size_t)EMB_ * KHT_ * 2);
    unsigned short* WtT     = (unsigned short*)alloc((size_t)EMB_ * KHT_ * 2);
    unsigned short* WtB     = (unsigned short*)alloc((size_t)NPAD_ * KBIL_ * 2);
    unsigned short* Xh      = (unsigned short*)alloc((size_t)B_ * P_ * KHT_ * 2);
    unsigned short* Xt      = (unsigned short*)alloc((size_t)B_ * P_ * KHT_ * 2);
    unsigned short* hsB     = (unsigned short*)alloc((size_t)B_ * P_ * EMB_ * 2);
    unsigned short* tsB     = (unsigned short*)alloc((size_t)B_ * P_ * EMB_ * 2);
    float*          logitsF = (float*)alloc((size_t)B_ * P_ * NPAD_ * 4);
    float*          enth    = (float*)alloc((size_t)B_ * E_ * DNT_ * 4);

    dim3 blk(256);
    k_prep<<<PREP_TBIL, blk, 0, stream>>>(
        seq, att, epos, spos, vpos, ntype, W_head, W_tail, W_bil,
        enth, e_att, seqT, WtH, WtT, WtB,
        d_out, mention_off, sent_off, virt_off);
    k_mid<<<2 * B_ * P_ + 256, blk, 0, stream>>>(e_att, enth, hts, htb, Xh, Xt, logitsF);
    // rs GEMM: per batch [512 x 1024] @ [1024 x 768]^T -> X cols 1024..1791
    k_gemm<<<dim3(EMB_ / 64, P_ / 64, B_), blk, 0, stream>>>(
        htb, nullptr, seqT, nullptr, C_, C_,
        (long long)P_ * C_, (long long)D_ * C_, C_ / 32, 0,
        nullptr, nullptr, nullptr, nullptr, Xh, Xt, seq);
    // fused head+tail: [2048 x 1792] @ [1792 x 768]^T, tanh+bias -> bf16 hsB/tsB
    k_gemm<<<dim3(EMB_ / 64, (B_ * P_) / 64, 2), blk, 0, stream>>>(
        Xh, Xt, WtH, WtT, KHT_, KHT_, 0, 0, KHT_ / 32, 1,
        b_head, b_tail, hsB, tsB, nullptr, nullptr, seq);
    // bilinear: 384 blocks (32 m-tiles x 12 groups), XCD-affine, 512 threads
    k_bil<<<dim3((B_ * P_ / 64) * 12), dim3(512), 0, stream>>>(hsB, tsB, WtB, logitsF);
    k_fin<<<(B_ * P_ * NL_ + 255) / 256, blk, 0, stream>>>(logitsF, b_bil, d_out, seq);
}